// Round 15
// baseline (375.865 us; speedup 1.0000x reference)
//
#include <hip/hip_runtime.h>
#include <hip/hip_bf16.h>
#include <cstdint>
#include <cstddef>
#include <cmath>

typedef __bf16 bf16_t;
typedef __bf16 bf16x8 __attribute__((ext_vector_type(8)));
typedef __bf16 bf16x4v __attribute__((ext_vector_type(4)));
typedef float f32x4 __attribute__((ext_vector_type(4)));

#define B_SZ 4
#define L_SZ 4096
#define H_SZ 2048
#define R_SZ 256
// exp(S) with S = acc/16  ->  2^(acc * log2(e)/16)
#define EXP_SC 0.090168440f
// E pair-panel geometry: pair P holds 256 rows x (P+1)*256 cols bf16
#define E2_ELEMS 8912896L   // 65536 * (1+2+...+16) elements per batch
#define E2_BYTES 17825792L
#define LDS_BYTES 131072    // A 4 half-slots (64K) + B 4 half-slots (64K)

// async global->LDS, 16B per lane. LDS dest must be wave-uniform base (+lane*16 by HW).
#define GLDS16(gaddr, laddr)                                                    \
  __builtin_amdgcn_global_load_lds(                                             \
      (const __attribute__((address_space(1))) void*)(gaddr),                   \
      (__attribute__((address_space(3))) void*)(laddr), 16, 0, 0)

__device__ __forceinline__ f32x4 mfma16(bf16x8 a, bf16x8 b, f32x4 c) {
  return __builtin_amdgcn_mfma_f32_16x16x32_bf16(a, b, c, 0, 0, 0);
}

__device__ __forceinline__ float rsum16(float v) {
  v += __shfl_xor(v, 1, 16);
  v += __shfl_xor(v, 2, 16);
  v += __shfl_xor(v, 4, 16);
  v += __shfl_xor(v, 8, 16);
  return v;
}

// ---------------- conversion kernel (block-range partitioned, coalesced transpose) --------
__global__ void conv_kernel(const float* __restrict__ x, const float* __restrict__ Ws,
                            const float* __restrict__ Wa, const float* __restrict__ Wo,
                            bf16_t* __restrict__ xb, bf16_t* __restrict__ Wst,
                            bf16_t* __restrict__ Wat, bf16_t* __restrict__ Wob,
                            float* __restrict__ lsum) {
  const int bid = blockIdx.x;
  const int t = threadIdx.x;
  if (bid < 1280) {
    const int tid = bid * 256 + t;
    const int stride = 1280 * 256;
    const int n4 = B_SZ * L_SZ * H_SZ / 4;
    for (int i = tid; i < n4; i += stride) {
      float4 v = reinterpret_cast<const float4*>(x)[i];
      bf16x4v o;
      o[0] = (bf16_t)v.x; o[1] = (bf16_t)v.y; o[2] = (bf16_t)v.z; o[3] = (bf16_t)v.w;
      reinterpret_cast<bf16x4v*>(xb)[i] = o;
    }
  } else if (bid < 1920) {
    const int tid = (bid - 1280) * 256 + t;
    const int stride = 640 * 256;
    for (int idx = tid; idx < H_SZ * H_SZ / 4; idx += stride) {
      float4 v = reinterpret_cast<const float4*>(Wo)[idx];
      bf16x4v o;
      o[0] = (bf16_t)v.x; o[1] = (bf16_t)v.y; o[2] = (bf16_t)v.z; o[3] = (bf16_t)v.w;
      reinterpret_cast<bf16x4v*>(Wob)[idx] = o;
    }
  } else if (bid < 2040) {
    __shared__ float tile[32][33];
    const int j = t & 31;
    const int i4 = t >> 5;
    for (int tt = bid - 1920; tt < 1024; tt += 120) {
      const int mat = tt >> 9;
      const int ti = tt & 511;
      const int h0 = (ti >> 3) * 32;
      const int r0 = (ti & 7) * 32;
      const float* src = mat ? Wa : Ws;
      bf16_t* dst = mat ? Wat : Wst;
      __syncthreads();
#pragma unroll
      for (int p = 0; p < 4; ++p) {
        const int ii = p * 8 + i4;
        tile[ii][j] = src[(long)(h0 + ii) * R_SZ + r0 + j];
      }
      __syncthreads();
#pragma unroll
      for (int p = 0; p < 4; ++p) {
        const int rr = p * 8 + i4;
        dst[(long)(r0 + rr) * H_SZ + h0 + j] = (bf16_t)tile[j][rr];
      }
    }
  } else {
    const int tid = (bid - 2040) * 256 + t;
    const int stride = 8 * 256;
    for (int idx = tid; idx < B_SZ * L_SZ; idx += stride) lsum[idx] = 0.0f;
  }
}

// ===== 256x256 GEMM core — m201-template 4-phase schedule (R15) =====
// C[m,n] = sum_k A[m,k] B[n,k]. K = NT*64 (NT >= 4). 512 threads = 8 waves (2M x 4N).
// LDS 128 KiB: A [0,64K) = 4 half-slots (A M-half h of tile T at (T&1)*32K + h*16K);
// B [64K,128K) mirrored (N-halves). Half-slot = 128 rows x 128 B linear; swizzle via
// pre-swizzled global source; reads XOR the same mask.
//
// FULLN=true: exact m201 template — 4 phases/K-tile, each {reads; stage 1 half (2 gloads);
// [lgkmcnt(8) if 12 reads]; barrier; lgkmcnt(0); setprio; 16 MFMA; setprio; barrier};
// vmcnt(6) ONLY at q4 (3 half-tiles in flight). Stage map: q1->B1(T+1), q2->A0(T+2),
// q3->B0(T+2), q4->A1(T+2).
// Certification induction: q4's vmcnt(6) retires everything except stages from this tile's
// q2,q3,q4 => exactly tile T+1's four halves certified at T.q4 (B1(T+1) from T.q1; A0/B0/A1
// (T+1) from T-1.q2/q3/q4). Reads at T+1.q1..q3 therefore all post-certification.
// WAR: each stage targets a slot whose reads drained >=1 barrier earlier (q2 stage->A0(T)'s
// slot read q1; q3->B0(T)'s slot read q1; q4->A1(T)'s slot read q3; q1->B1(T-1)'s slot).
// Prologue: stage tile0 (4 halves) + A0,B0,A1 of tile1; vmcnt(6) retires tile0.
// Tails: T=NT-2 stages only B1(NT-1), q4 vmcnt(0); T=NT-1 computes only.
// MFMA order identical to prior rounds -> bit-identical output.
//
// FULLN=false (N=128, QK): proven R12/R14 2-region body (stage T+1.h1 in r1, T+2.h0 in r2,
// vmcnt(4)); B-h1 never staged/read, NH=1 MFMAs skipped.

#define G8_STG(P, REGION, BUFOFF, HALF)                                        \
  GLDS16((P)[0], lds + (REGION) + (BUFOFF) + (HALF)*16384 + ldst0);            \
  GLDS16((P)[1], lds + (REGION) + (BUFOFF) + (HALF)*16384 + ldst1);            \
  (P)[0] += 128; (P)[1] += 128;

#define G8_LDA(MH, BO) {                                                       \
  const char* ap_ = lds + (BO) + (MH)*16384;                                   \
  fa[0][0] = *(const bf16x8*)(ap_ + aOff0);                                    \
  fa[0][1] = *(const bf16x8*)(ap_ + aOff1);                                    \
  fa[1][0] = *(const bf16x8*)(ap_ + 4096 + aOff0);                             \
  fa[1][1] = *(const bf16x8*)(ap_ + 4096 + aOff1);                             \
  fa[2][0] = *(const bf16x8*)(ap_ + 8192 + aOff0);                             \
  fa[2][1] = *(const bf16x8*)(ap_ + 8192 + aOff1);                             \
  fa[3][0] = *(const bf16x8*)(ap_ + 12288 + aOff0);                            \
  fa[3][1] = *(const bf16x8*)(ap_ + 12288 + aOff1); }

#define G8_LDB(NH, BO) {                                                       \
  const char* bp_ = lds + 65536 + (BO) + (NH)*16384;                           \
  fb[NH][0][0] = *(const bf16x8*)(bp_ + bOff0);                                \
  fb[NH][0][1] = *(const bf16x8*)(bp_ + bOff1);                                \
  fb[NH][1][0] = *(const bf16x8*)(bp_ + 8192 + bOff0);                         \
  fb[NH][1][1] = *(const bf16x8*)(bp_ + 8192 + bOff1); }

#define G8_MM1(AM, AN, MF, NH, J)                                              \
  acc[AM][AN] = mfma16(fa[MF][1], fb[NH][J][1],                                \
                 mfma16(fa[MF][0], fb[NH][J][0], acc[AM][AN]))

#define G8_MM(MH, NH)                                                          \
  G8_MM1((MH)*4+0, (NH)*2+0, 0, NH, 0); G8_MM1((MH)*4+0, (NH)*2+1, 0, NH, 1); \
  G8_MM1((MH)*4+1, (NH)*2+0, 1, NH, 0); G8_MM1((MH)*4+1, (NH)*2+1, 1, NH, 1); \
  G8_MM1((MH)*4+2, (NH)*2+0, 2, NH, 0); G8_MM1((MH)*4+2, (NH)*2+1, 2, NH, 1); \
  G8_MM1((MH)*4+3, (NH)*2+0, 3, NH, 0); G8_MM1((MH)*4+3, (NH)*2+1, 3, NH, 1)

#define G8_BAR()                                                               \
  __builtin_amdgcn_sched_barrier(0);                                           \
  __builtin_amdgcn_s_barrier();

#define G8_MFMA_PHASE(MH, NH)                                                  \
  asm volatile("s_waitcnt lgkmcnt(0)" ::: "memory");                           \
  __builtin_amdgcn_sched_barrier(0);                                           \
  __builtin_amdgcn_s_setprio(1);                                               \
  G8_MM(MH, NH);                                                               \
  __builtin_amdgcn_s_setprio(0);                                               \
  G8_BAR();

template <bool FULLN>
__device__ __forceinline__ void gemm8_core(
    const char* Ag, const char* Bg, long aRowB, long bRowB, int NT,
    char* lds, f32x4 (&acc)[8][4])
{
  const int t = threadIdx.x;
  const int l = t & 63;
  const int wid = t >> 6;
  const int wr = wid >> 2;
  const int wc = wid & 3;
  const int l15 = l & 15;
  const int l4 = l >> 4;
  const int swzm = (l15 & 7) << 4;
  const int aOff0 = (wr * 16 + l15) * 128 + ((l4 * 16) ^ swzm);
  const int aOff1 = (wr * 16 + l15) * 128 + ((64 + l4 * 16) ^ swzm);
  const int bOff0 = (wc * 16 + l15) * 128 + ((l4 * 16) ^ swzm);
  const int bOff1 = (wc * 16 + l15) * 128 + ((64 + l4 * 16) ^ swzm);
  // staging: per-thread, 2 x 16B per half-tile; d = t*16 + i*8192 covers [0,16K) linear
  const int d0 = t * 16, d1 = t * 16 + 8192;
  const int r0 = d0 >> 7, r1 = d1 >> 7;
  const int s0 = (d0 & 127) ^ ((r0 & 7) << 4);
  const int s1 = (d1 & 127) ^ ((r1 & 7) << 4);
  const char* pA0[2] = { Ag + (long)r0 * aRowB + s0, Ag + (long)r1 * aRowB + s1 };
  const char* pA1[2] = { Ag + (long)(128 + r0) * aRowB + s0, Ag + (long)(128 + r1) * aRowB + s1 };
  const char* pB0[2] = { Bg + (long)r0 * bRowB + s0, Bg + (long)r1 * bRowB + s1 };
  const char* pB1[2] = { Bg + (long)(128 + r0) * bRowB + s0, Bg + (long)(128 + r1) * bRowB + s1 };
  const int ldst0 = wid * 1024, ldst1 = wid * 1024 + 8192;
  bf16x8 fa[4][2], fb[2][2][2];

  if constexpr (FULLN) {
    // prologue: tile0 (A0,A1,B0,B1) then tile1 (A0,B0,A1); vmcnt(6) retires tile0.
    G8_STG(pA0, 0, 0, 0);
    G8_STG(pA1, 0, 0, 1);
    G8_STG(pB0, 65536, 0, 0);
    G8_STG(pB1, 65536, 0, 1);
    G8_STG(pA0, 0, 32768, 0);
    G8_STG(pB0, 65536, 32768, 0);
    G8_STG(pA1, 0, 32768, 1);
    asm volatile("s_waitcnt vmcnt(6)" ::: "memory");
    G8_BAR();

    int bufOff = 0;
    for (int T = 0; T < NT; ++T) {
      const int ob = bufOff ^ 32768;
      const bool g1 = (T < NT - 1);
      const bool g2 = (T < NT - 2);
      // ---- q1: reads A-h0 (8) + B-h0 (4); stage B1(T+1) ----
      G8_LDA(0, bufOff);
      G8_LDB(0, bufOff);
      if (g1) { G8_STG(pB1, 65536, ob, 1); }
      asm volatile("s_waitcnt lgkmcnt(8)" ::: "memory");
      G8_BAR();
      G8_MFMA_PHASE(0, 0);
      // ---- q2: reads B-h1 (4); stage A0(T+2) ----
      G8_LDB(1, bufOff);
      if (g2) { G8_STG(pA0, 0, bufOff, 0); }
      G8_BAR();
      G8_MFMA_PHASE(0, 1);
      // ---- q3: reads A-h1 (8); stage B0(T+2) ----
      G8_LDA(1, bufOff);
      if (g2) { G8_STG(pB0, 65536, bufOff, 0); }
      G8_BAR();
      G8_MFMA_PHASE(1, 0);
      // ---- q4: stage A1(T+2); counted vmcnt certifies tile T+1 ----
      if (g2) {
        G8_STG(pA1, 0, bufOff, 1);
        asm volatile("s_waitcnt vmcnt(6)" ::: "memory");
      } else if (g1) {
        asm volatile("s_waitcnt vmcnt(0)" ::: "memory");
      }
      G8_BAR();
      __builtin_amdgcn_s_setprio(1);
      G8_MM(1, 1);
      __builtin_amdgcn_s_setprio(0);
      G8_BAR();
      bufOff = ob;
    }
  } else {
    // 2-region body (R12/R14, measured-good for half-N)
    G8_STG(pA0, 0, 0, 0);
    G8_STG(pA1, 0, 0, 1);
    G8_STG(pB0, 65536, 0, 0);
    G8_STG(pA0, 0, 32768, 0);
    G8_STG(pB0, 65536, 32768, 0);
    asm volatile("s_waitcnt vmcnt(4)" ::: "memory");
    G8_BAR();

    int bufOff = 0;
    for (int T = 0; T < NT; ++T) {
      const int ob = bufOff ^ 32768;
      const bool g1 = (T < NT - 1);
      const bool g2 = (T < NT - 2);
      // r1
      G8_LDA(0, bufOff);
      G8_LDB(0, bufOff);
      if (g1) { G8_STG(pA1, 0, ob, 1); }
      __builtin_amdgcn_s_setprio(1);
      G8_MM(0, 0);
      __builtin_amdgcn_s_setprio(0);
      G8_LDA(1, bufOff);
      G8_BAR();
      // r2
      if (g2) {
        G8_STG(pA0, 0, bufOff, 0);
        G8_STG(pB0, 65536, bufOff, 0);
      }
      __builtin_amdgcn_s_setprio(1);
      G8_MM(1, 0);
      __builtin_amdgcn_s_setprio(0);
      if (g2) {
        asm volatile("s_waitcnt vmcnt(4)" ::: "memory");
      } else if (g1) {
        asm volatile("s_waitcnt vmcnt(0)" ::: "memory");
      }
      G8_BAR();
      bufOff = ob;
    }
  }
}

// ---------------- fused V'+QK GEMM kernel ----------------
// Flat grid 768 = 512 V' full blocks (f<512, XCD-chunked) + 256 QK half-N blocks (f>=512,
// N=128). Exactly 3 blocks/CU.
__global__ __launch_bounds__(512) void vq8_kernel(
    const bf16_t* __restrict__ Wob, const bf16_t* __restrict__ xb, bf16_t* __restrict__ VT,
    const bf16_t* __restrict__ Wst, const bf16_t* __restrict__ Wat,
    bf16_t* __restrict__ Qb, bf16_t* __restrict__ Kb)
{
  extern __shared__ char lds[];
  const int f = blockIdx.x;
  const int t = threadIdx.x, l = t & 63, wid = t >> 6;
  const int wr = wid >> 2, wc = wid & 3, l15 = l & 15, l4 = l >> 4;
  f32x4 acc[8][4] = {};
  if (f < 512) {
    const int lg = (f & 7) * 64 + (f >> 3);   // bijective (512 = 8*64)
    const int xo = lg & 7;
    const int yj = (lg >> 3) & 15;
    const int b  = lg >> 7;
    const long mBase = (long)xo * 256;        // o
    const long nBase = (long)yj * 256;        // j
    gemm8_core<true>((const char*)Wob + mBase * (H_SZ * 2),
                     (const char*)xb + ((long)b * L_SZ + nBase) * (H_SZ * 2),
                     H_SZ * 2, H_SZ * 2, H_SZ / 64, lds, acc);
    bf16_t* Cp = VT + (long)b * H_SZ * L_SZ;
#pragma unroll
    for (int am = 0; am < 8; ++am) {
#pragma unroll
      for (int an = 0; an < 4; ++an) {
        const long row = mBase + wr * 16 + am * 32 + l4 * 4;
        const long col = nBase + wc * 16 + an * 64 + l15;
#pragma unroll
        for (int r = 0; r < 4; ++r)
          Cp[(row + r) * L_SZ + col] = (bf16_t)acc[am][an][r];
      }
    }
  } else {
    const int qf = f - 512;                   // 0..255
    const int lg = (qf & 7) * 32 + (qf >> 3); // bijective (256 = 8*32)
    const int m = lg & 63;
    const int n = (lg >> 6) & 1;
    const int proj = lg >> 7;
    const long mBase = (long)m * 256;
    const long nBase = (long)n * 128;
    const bf16_t* W = proj ? Wat : Wst;
    bf16_t* Cp = proj ? Kb : Qb;
    gemm8_core<false>((const char*)xb + mBase * (H_SZ * 2),
                      (const char*)W + nBase * (H_SZ * 2),
                      H_SZ * 2, H_SZ * 2, H_SZ / 64, lds, acc);
#pragma unroll
    for (int am = 0; am < 8; ++am) {
#pragma unroll
      for (int an = 0; an < 2; ++an) {
        const long row = mBase + wr * 16 + am * 32 + l4 * 4;
        const long col = nBase + wc * 16 + an * 64 + l15;
#pragma unroll
        for (int r = 0; r < 4; ++r)
          Cp[(row + r) * R_SZ + col] = (bf16_t)acc[am][an][r];
      }
    }
  }
}

// ---------------- pass 1: E = exp(Q K^T / 16) (causal) pair-panels + row sums ----------------
// Flat grid 544 (= 4 b x 136 triangular tiles), XCD-chunked so same-Q-panel blocks share an L2.
__global__ __launch_bounds__(512) void ep8_kernel(
    const bf16_t* __restrict__ Qb, const bf16_t* __restrict__ Kb,
    bf16_t* __restrict__ E, float* __restrict__ lsum)
{
  extern __shared__ char lds[];
  const int f = blockIdx.x;                  // 0..543
  const int lg = (f & 7) * 68 + (f >> 3);    // bijective (544 = 8*68)
  const int b = lg / 136;
  const int t136 = lg - b * 136;
  int P = (int)((sqrtf((float)(8 * t136 + 1)) - 1.0f) * 0.5f);
  while ((P + 1) * (P + 2) / 2 <= t136) ++P;
  while (P * (P + 1) / 2 > t136) --P;
  const int Jp = t136 - P * (P + 1) / 2;     // 0..P

  f32x4 acc[8][4] = {};
  gemm8_core<true>((const char*)Qb + ((long)b * L_SZ + P * 256) * (R_SZ * 2),
                   (const char*)Kb + ((long)b * L_SZ + Jp * 256) * (R_SZ * 2),
                   R_SZ * 2, R_SZ * 2, R_SZ / 64, lds, acc);
  const int t = threadIdx.x, l = t & 63, wid = t >> 6;
  const int wr = wid >> 2, wc = wid & 3, l15 = l & 15, l4 = l >> 4;
  bf16_t* Ep = E + (long)b * E2_ELEMS + 32768L * P * (P + 1);
  const long ldaE = (long)(P + 1) * 256;
  float* lp = lsum + (long)b * L_SZ + P * 256;
  const bool diag = (Jp == P);
#pragma unroll
  for (int am = 0; am < 8; ++am) {
    const int rowi = wr * 16 + am * 32 + l4 * 4;   // 0..255 within pair rows
#pragma unroll
    for (int r = 0; r < 4; ++r) {
      float s = 0.0f;
#pragma unroll
      for (int an = 0; an < 4; ++an) {
        const int coli = wc * 16 + an * 64 + l15;
        float p = exp2f(acc[am][an][r] * EXP_SC);
        if (diag && coli > rowi + r) p = 0.0f;     // jj > ii (same 256-tile)
        Ep[(long)(rowi + r) * ldaE + Jp * 256 + coli] = (bf16_t)p;
        s += p;
      }
      s = rsum16(s);
      if (l15 == 0) atomicAdd(lp + rowi + r, s);
    }
  }
}

// ---------------- pass 2: out = (E @ V'^T) / l + bo, paired tiles for balance ----------------
// Flat grid 256; XCD-chunked swizzle: each XCD gets 4 pr-pairs x 8 j-slices, one b.
__global__ __launch_bounds__(512) void pv8_kernel(
    const bf16_t* __restrict__ E, const bf16_t* __restrict__ VT,
    const float* __restrict__ lsum, const float* __restrict__ bo,
    float* __restrict__ out)
{
  extern __shared__ char lds[];
  const int f = blockIdx.x;                 // 0..255
  const int lg = (f & 7) * 32 + (f >> 3);   // bijective (256 = 8*32)
  const int yj = lg & 7;
  const int pr = (lg >> 3) & 7;
  const int b  = lg >> 6;
  const int nBase = yj * 256;
  const int t = threadIdx.x, l = t & 63, wid = t >> 6;
  const int wr = wid >> 2, wc = wid & 3, l15 = l & 15, l4 = l >> 4;

#pragma unroll
  for (int s = 0; s < 2; ++s) {
    const int mt = s ? pr : (15 - pr);
    f32x4 acc[8][4] = {};
    const char* Ag = (const char*)E + (long)b * E2_BYTES + 65536L * mt * (mt + 1);
    const char* Bg = (const char*)VT + ((long)b * H_SZ + nBase) * (L_SZ * 2);
    gemm8_core<true>(Ag, Bg, (long)(mt + 1) * 512, L_SZ * 2, (mt + 1) * 4, lds, acc);
#pragma unroll
    for (int am = 0; am < 8; ++am) {
      const long rowG = (long)b * L_SZ + mt * 256 + wr * 16 + am * 32 + l4 * 4;
      float linv[4];
#pragma unroll
      for (int r = 0; r < 4; ++r) linv[r] = 1.0f / lsum[rowG + r];
#pragma unroll
      for (int an = 0; an < 4; ++an) {
        const int col = nBase + wc * 16 + an * 64 + l15;
        const float bias = bo[col];
#pragma unroll
        for (int r = 0; r < 4; ++r)
          out[(rowG + r) * H_SZ + col] = acc[am][an][r] * linv[r] + bias;
      }
    }
  }
}

extern "C" void kernel_launch(void* const* d_in, const int* in_sizes, int n_in,
                              void* d_out, int out_size, void* d_ws, size_t ws_size,
                              hipStream_t stream) {
  const float* x  = (const float*)d_in[0];
  const float* Ws = (const float*)d_in[1];
  const float* Wa = (const float*)d_in[2];
  const float* Wo = (const float*)d_in[3];
  const float* bo = (const float*)d_in[4];
  float* out = (float*)d_out;

  char* ws = (char*)d_ws;
  // layout (bytes):
  //   [0, 64M)        xb   (dead after V'/QK)  -- aliased by E pair-panels
  //   [64M, 65M)      Wst  (dead after QK)     -- aliased by E
  //   [65M, 66M)      Wat  (dead after QK)     -- aliased by E
  //   [66M, 74M)      Wob  (dead after V')     -- head aliased by E (E = 71.3MB < 74M)
  //   [74M, 82M)      Qb
  //   [82M, 90M)      Kb
  //   [90M, 154M)     VT
  //   [154M, +64K)    lsum
  bf16_t* xb  = (bf16_t*)(ws + 0);
  bf16_t* Wst = (bf16_t*)(ws + 67108864);
  bf16_t* Wat = (bf16_t*)(ws + 68157440);
  bf16_t* Wob = (bf16_t*)(ws + 69206016);
  bf16_t* Qb  = (bf16_t*)(ws + 77594624);
  bf16_t* Kb  = (bf16_t*)(ws + 85983232);
  bf16_t* VT  = (bf16_t*)(ws + 94371840);
  float*  lsum = (float*)(ws + 161480704);
  bf16_t* E   = (bf16_t*)(ws + 0);

  hipFuncSetAttribute((const void*)vq8_kernel, hipFuncAttributeMaxDynamicSharedMemorySize, LDS_BYTES);
  hipFuncSetAttribute((const void*)ep8_kernel, hipFuncAttributeMaxDynamicSharedMemorySize, LDS_BYTES);
  hipFuncSetAttribute((const void*)pv8_kernel, hipFuncAttributeMaxDynamicSharedMemorySize, LDS_BYTES);

  // conversions + lsum init (block-range partitioned; LDS-tiled Ws/Wa transpose)
  conv_kernel<<<dim3(2048), dim3(256), 0, stream>>>(x, Ws, Wa, Wo, xb, Wst, Wat, Wob, lsum);
  // fused: V'^T = Wo . x (512 full blocks) + Q = x @ Ws, K = x @ Wa (256 half-N blocks)
  vq8_kernel<<<dim3(768), dim3(512), LDS_BYTES, stream>>>(Wob, xb, VT, Wst, Wat, Qb, Kb);
  // pass 1: E = exp(QK^T/16) causal pair-panels + row sums (E aliases xb/W* — all dead now)
  ep8_kernel<<<dim3(544), dim3(512), LDS_BYTES, stream>>>(Qb, Kb, E, lsum);
  // pass 2: out = E @ V'^T / l + bo  (XCD-swizzled flat grid)
  pv8_kernel<<<dim3(256), dim3(512), LDS_BYTES, stream>>>(E, VT, lsum, bo, out);
}

// Round 16
// 366.164 us; speedup vs baseline: 1.0265x; 1.0265x over previous
//
#include <hip/hip_runtime.h>
#include <hip/hip_bf16.h>
#include <cstdint>
#include <cstddef>
#include <cmath>

typedef __bf16 bf16_t;
typedef __bf16 bf16x8 __attribute__((ext_vector_type(8)));
typedef __bf16 bf16x4v __attribute__((ext_vector_type(4)));
typedef float f32x4 __attribute__((ext_vector_type(4)));

#define B_SZ 4
#define L_SZ 4096
#define H_SZ 2048
#define R_SZ 256
// exp(S) with S = acc/16  ->  2^(acc * log2(e)/16)
#define EXP_SC 0.090168440f
// E pair-panel geometry: pair P holds 256 rows x (P+1)*256 cols bf16
#define E2_ELEMS 8912896L   // 65536 * (1+2+...+16) elements per batch
#define E2_BYTES 17825792L
#define LDS_BYTES 163840    // A ring-4 (64K) + B ring-6 (96K)

// async global->LDS, 16B per lane. LDS dest must be wave-uniform base (+lane*16 by HW).
#define GLDS16(gaddr, laddr)                                                    \
  __builtin_amdgcn_global_load_lds(                                             \
      (const __attribute__((address_space(1))) void*)(gaddr),                   \
      (__attribute__((address_space(3))) void*)(laddr), 16, 0, 0)

__device__ __forceinline__ f32x4 mfma16(bf16x8 a, bf16x8 b, f32x4 c) {
  return __builtin_amdgcn_mfma_f32_16x16x32_bf16(a, b, c, 0, 0, 0);
}

__device__ __forceinline__ float rsum16(float v) {
  v += __shfl_xor(v, 1, 16);
  v += __shfl_xor(v, 2, 16);
  v += __shfl_xor(v, 4, 16);
  v += __shfl_xor(v, 8, 16);
  return v;
}

// ---------------- conversion kernel (block-range partitioned, coalesced transpose) --------
__global__ void conv_kernel(const float* __restrict__ x, const float* __restrict__ Ws,
                            const float* __restrict__ Wa, const float* __restrict__ Wo,
                            bf16_t* __restrict__ xb, bf16_t* __restrict__ Wst,
                            bf16_t* __restrict__ Wat, bf16_t* __restrict__ Wob,
                            float* __restrict__ lsum) {
  const int bid = blockIdx.x;
  const int t = threadIdx.x;
  if (bid < 1280) {
    const int tid = bid * 256 + t;
    const int stride = 1280 * 256;
    const int n4 = B_SZ * L_SZ * H_SZ / 4;
    for (int i = tid; i < n4; i += stride) {
      float4 v = reinterpret_cast<const float4*>(x)[i];
      bf16x4v o;
      o[0] = (bf16_t)v.x; o[1] = (bf16_t)v.y; o[2] = (bf16_t)v.z; o[3] = (bf16_t)v.w;
      reinterpret_cast<bf16x4v*>(xb)[i] = o;
    }
  } else if (bid < 1920) {
    const int tid = (bid - 1280) * 256 + t;
    const int stride = 640 * 256;
    for (int idx = tid; idx < H_SZ * H_SZ / 4; idx += stride) {
      float4 v = reinterpret_cast<const float4*>(Wo)[idx];
      bf16x4v o;
      o[0] = (bf16_t)v.x; o[1] = (bf16_t)v.y; o[2] = (bf16_t)v.z; o[3] = (bf16_t)v.w;
      reinterpret_cast<bf16x4v*>(Wob)[idx] = o;
    }
  } else if (bid < 2040) {
    __shared__ float tile[32][33];
    const int j = t & 31;
    const int i4 = t >> 5;
    for (int tt = bid - 1920; tt < 1024; tt += 120) {
      const int mat = tt >> 9;
      const int ti = tt & 511;
      const int h0 = (ti >> 3) * 32;
      const int r0 = (ti & 7) * 32;
      const float* src = mat ? Wa : Ws;
      bf16_t* dst = mat ? Wat : Wst;
      __syncthreads();
#pragma unroll
      for (int p = 0; p < 4; ++p) {
        const int ii = p * 8 + i4;
        tile[ii][j] = src[(long)(h0 + ii) * R_SZ + r0 + j];
      }
      __syncthreads();
#pragma unroll
      for (int p = 0; p < 4; ++p) {
        const int rr = p * 8 + i4;
        dst[(long)(r0 + rr) * H_SZ + h0 + j] = (bf16_t)tile[j][rr];
      }
    }
  } else {
    const int tid = (bid - 2040) * 256 + t;
    const int stride = 8 * 256;
    for (int idx = tid; idx < B_SZ * L_SZ; idx += stride) lsum[idx] = 0.0f;
  }
}

// ===== 256x256 GEMM core — 2-barrier tile, B ring-6, compiler-managed lgkm waits (R14) =====
// C[m,n] = sum_k A[m,k] B[n,k]. K = NT*64 (NT >= 4). 512 threads = 8 waves (2M x 4N).
// LDS 160 KiB: A [0,64K) = 4 half-slots (slot = A-half h & 3); B [64K,160K) = 6 half-slots
// (slot = B-half h % 6). Half-slot = 128 rows x 128 B linear, swizzle via pre-swizzled
// global source; reads XOR the same mask. FULLN=false -> N=128.
// No explicit lgkmcnt waits in the steady loop: every ds_read is consumed by an MFMA in its
// own region, so the compiler's per-MFMA counted lgkmcnt waits give minimal head stall and
// guarantee reads drain before the region-end barrier. vmcnt certification per R13's
// induction. Measured best: 366.2 µs total (R14).

#define G8_STG(P, REGION, BUFOFF, HALF)                                        \
  GLDS16((P)[0], lds + (REGION) + (BUFOFF) + (HALF)*16384 + ldst0);            \
  GLDS16((P)[1], lds + (REGION) + (BUFOFF) + (HALF)*16384 + ldst1);            \
  (P)[0] += 128; (P)[1] += 128;

// B stage into ring slot S (0..5)
#define GB_STG(P, S)                                                           \
  GLDS16((P)[0], lds + 65536 + (S)*16384 + ldst0);                             \
  GLDS16((P)[1], lds + 65536 + (S)*16384 + ldst1);                             \
  (P)[0] += 128; (P)[1] += 128;

#define G8_LDA(MH, BO) {                                                       \
  const char* ap_ = lds + (BO) + (MH)*16384;                                   \
  fa[0][0] = *(const bf16x8*)(ap_ + aOff0);                                    \
  fa[0][1] = *(const bf16x8*)(ap_ + aOff1);                                    \
  fa[1][0] = *(const bf16x8*)(ap_ + 4096 + aOff0);                             \
  fa[1][1] = *(const bf16x8*)(ap_ + 4096 + aOff1);                             \
  fa[2][0] = *(const bf16x8*)(ap_ + 8192 + aOff0);                             \
  fa[2][1] = *(const bf16x8*)(ap_ + 8192 + aOff1);                             \
  fa[3][0] = *(const bf16x8*)(ap_ + 12288 + aOff0);                            \
  fa[3][1] = *(const bf16x8*)(ap_ + 12288 + aOff1); }

// B frag read from ring slot S+NH
#define G8_LDB(NH, S) {                                                        \
  const char* bp_ = lds + 65536 + ((S) + (NH)) * 16384;                        \
  fb[NH][0][0] = *(const bf16x8*)(bp_ + bOff0);                                \
  fb[NH][0][1] = *(const bf16x8*)(bp_ + bOff1);                                \
  fb[NH][1][0] = *(const bf16x8*)(bp_ + 8192 + bOff0);                         \
  fb[NH][1][1] = *(const bf16x8*)(bp_ + 8192 + bOff1); }

#define G8_MM1(AM, AN, MF, NH, J)                                              \
  acc[AM][AN] = mfma16(fa[MF][1], fb[NH][J][1],                                \
                 mfma16(fa[MF][0], fb[NH][J][0], acc[AM][AN]))

#define G8_MM(MH, NH)                                                          \
  G8_MM1((MH)*4+0, (NH)*2+0, 0, NH, 0); G8_MM1((MH)*4+0, (NH)*2+1, 0, NH, 1); \
  G8_MM1((MH)*4+1, (NH)*2+0, 1, NH, 0); G8_MM1((MH)*4+1, (NH)*2+1, 1, NH, 1); \
  G8_MM1((MH)*4+2, (NH)*2+0, 2, NH, 0); G8_MM1((MH)*4+2, (NH)*2+1, 2, NH, 1); \
  G8_MM1((MH)*4+3, (NH)*2+0, 3, NH, 0); G8_MM1((MH)*4+3, (NH)*2+1, 3, NH, 1)

template <bool FULLN>
__device__ __forceinline__ void gemm8_core(
    const char* Ag, const char* Bg, long aRowB, long bRowB, int NT,
    char* lds, f32x4 (&acc)[8][4])
{
  const int t = threadIdx.x;
  const int l = t & 63;
  const int wid = t >> 6;
  const int wr = wid >> 2;
  const int wc = wid & 3;
  const int l15 = l & 15;
  const int l4 = l >> 4;
  const int swzm = (l15 & 7) << 4;
  const int aOff0 = (wr * 16 + l15) * 128 + ((l4 * 16) ^ swzm);
  const int aOff1 = (wr * 16 + l15) * 128 + ((64 + l4 * 16) ^ swzm);
  const int bOff0 = (wc * 16 + l15) * 128 + ((l4 * 16) ^ swzm);
  const int bOff1 = (wc * 16 + l15) * 128 + ((64 + l4 * 16) ^ swzm);
  // staging: per-thread, 2 x 16B per half-tile; d = t*16 + i*8192 covers [0,16K) linear
  const int d0 = t * 16, d1 = t * 16 + 8192;
  const int r0 = d0 >> 7, r1 = d1 >> 7;
  const int s0 = (d0 & 127) ^ ((r0 & 7) << 4);
  const int s1 = (d1 & 127) ^ ((r1 & 7) << 4);
  const char* pA0[2] = { Ag + (long)r0 * aRowB + s0, Ag + (long)r1 * aRowB + s1 };
  const char* pA1[2] = { Ag + (long)(128 + r0) * aRowB + s0, Ag + (long)(128 + r1) * aRowB + s1 };
  const char* pB0[2] = { Bg + (long)r0 * bRowB + s0, Bg + (long)r1 * bRowB + s1 };
  const char* pB1[2] = { Bg + (long)(128 + r0) * bRowB + s0, Bg + (long)(128 + r1) * bRowB + s1 };
  const int ldst0 = wid * 1024, ldst1 = wid * 1024 + 8192;
  bf16x8 fa[4][2], fb[2][2][2];

  // prologue. Issue order matters for the counted vmcnt:
  //   group 1: A(0), A(1), B(0)[, B(1)]  -- tile 0, must retire before first barrier
  //   group 2: A(2), B(2)[, B(3)]        -- tile 1, stays in flight
  G8_STG(pA0, 0, 0, 0);          // A half 0 -> slot 0
  G8_STG(pA1, 0, 0, 1);          // A half 1 -> slot 1
  GB_STG(pB0, 0);                // B half 0 -> slot 0
  if constexpr (FULLN) { GB_STG(pB1, 1); }   // B half 1 -> slot 1
  G8_STG(pA0, 0, 32768, 0);      // A half 2 -> slot 2
  GB_STG(pB0, 2);                // B half 2 -> slot 2
  if constexpr (FULLN) { GB_STG(pB1, 3); }   // B half 3 -> slot 3
  if constexpr (FULLN) {
    asm volatile("s_waitcnt vmcnt(6)" ::: "memory");   // retire A(0),A(1),B(0),B(1)
  } else {
    asm volatile("s_waitcnt vmcnt(4)" ::: "memory");   // retire A(0),A(1),B(0)
  }
  __builtin_amdgcn_sched_barrier(0);
  __builtin_amdgcn_s_barrier();

  int bufOff = 0;   // A slot base: (2T)&3 halves -> byte offset {0,32768}
  int b0s = 0;      // B ring: (2T)%6
  for (int T = 0; T < NT; ++T) {
    const int ob = bufOff ^ 32768;
    const bool stg1 = (T < NT - 1);   // A(2T+3) exists
    const bool stg2 = (T < NT - 2);   // A(2T+4), B(2T+4), B(2T+5) exist
    const int s4 = (b0s + 4 >= 6) ? (b0s - 2) : (b0s + 4);   // slot of B half 2T+4
    // ---- region 1 ----
    G8_LDA(0, bufOff);
    G8_LDB(0, b0s);
    if constexpr (FULLN) { G8_LDB(1, b0s); }
    if (stg1) { G8_STG(pA1, 0, ob, 1); }           // A(2T+3)
    if (stg2) {
      GB_STG(pB0, s4);                              // B(2T+4)
      if constexpr (FULLN) { GB_STG(pB1, s4 + 1); } // B(2T+5)
    }
    __builtin_amdgcn_s_setprio(1);
    G8_MM(0, 0);
    if constexpr (FULLN) { G8_MM(0, 1); }
    __builtin_amdgcn_s_setprio(0);
    G8_LDA(1, bufOff);
    __builtin_amdgcn_sched_barrier(0);
    __builtin_amdgcn_s_barrier();
    // ---- region 2 ----
    if (stg2) { G8_STG(pA0, 0, bufOff, 0); }        // A(2T+4)
    __builtin_amdgcn_s_setprio(1);
    G8_MM(1, 0);
    if constexpr (FULLN) { G8_MM(1, 1); }
    __builtin_amdgcn_s_setprio(0);
    if (stg2) {
      // retire exactly tile T+1's halves; leave {B(2T+4),B(2T+5),A(2T+4)} in flight
      if constexpr (FULLN) {
        asm volatile("s_waitcnt vmcnt(6)" ::: "memory");
      } else {
        asm volatile("s_waitcnt vmcnt(4)" ::: "memory");
      }
    } else if (stg1) {
      asm volatile("s_waitcnt vmcnt(0)" ::: "memory");
    }
    __builtin_amdgcn_sched_barrier(0);
    __builtin_amdgcn_s_barrier();
    bufOff ^= 32768;
    b0s += 2; if (b0s >= 6) b0s -= 6;
  }
}

// ---------------- fused V'+QK GEMM kernel ----------------
// Flat grid 768 = 512 V' full blocks (f<512, XCD-chunked) + 256 QK half-N blocks (f>=512,
// N=128). Exactly 3 blocks/CU.
__global__ __launch_bounds__(512) void vq8_kernel(
    const bf16_t* __restrict__ Wob, const bf16_t* __restrict__ xb, bf16_t* __restrict__ VT,
    const bf16_t* __restrict__ Wst, const bf16_t* __restrict__ Wat,
    bf16_t* __restrict__ Qb, bf16_t* __restrict__ Kb)
{
  extern __shared__ char lds[];
  const int f = blockIdx.x;
  const int t = threadIdx.x, l = t & 63, wid = t >> 6;
  const int wr = wid >> 2, wc = wid & 3, l15 = l & 15, l4 = l >> 4;
  f32x4 acc[8][4] = {};
  if (f < 512) {
    const int lg = (f & 7) * 64 + (f >> 3);   // bijective (512 = 8*64)
    const int xo = lg & 7;
    const int yj = (lg >> 3) & 15;
    const int b  = lg >> 7;
    const long mBase = (long)xo * 256;        // o
    const long nBase = (long)yj * 256;        // j
    gemm8_core<true>((const char*)Wob + mBase * (H_SZ * 2),
                     (const char*)xb + ((long)b * L_SZ + nBase) * (H_SZ * 2),
                     H_SZ * 2, H_SZ * 2, H_SZ / 64, lds, acc);
    bf16_t* Cp = VT + (long)b * H_SZ * L_SZ;
#pragma unroll
    for (int am = 0; am < 8; ++am) {
#pragma unroll
      for (int an = 0; an < 4; ++an) {
        const long row = mBase + wr * 16 + am * 32 + l4 * 4;
        const long col = nBase + wc * 16 + an * 64 + l15;
#pragma unroll
        for (int r = 0; r < 4; ++r)
          Cp[(row + r) * L_SZ + col] = (bf16_t)acc[am][an][r];
      }
    }
  } else {
    const int qf = f - 512;                   // 0..255
    const int lg = (qf & 7) * 32 + (qf >> 3); // bijective (256 = 8*32)
    const int m = lg & 63;
    const int n = (lg >> 6) & 1;
    const int proj = lg >> 7;
    const long mBase = (long)m * 256;
    const long nBase = (long)n * 128;
    const bf16_t* W = proj ? Wat : Wst;
    bf16_t* Cp = proj ? Kb : Qb;
    gemm8_core<false>((const char*)xb + mBase * (H_SZ * 2),
                      (const char*)W + nBase * (H_SZ * 2),
                      H_SZ * 2, H_SZ * 2, H_SZ / 64, lds, acc);
#pragma unroll
    for (int am = 0; am < 8; ++am) {
#pragma unroll
      for (int an = 0; an < 2; ++an) {
        const long row = mBase + wr * 16 + am * 32 + l4 * 4;
        const long col = nBase + wc * 16 + an * 64 + l15;
#pragma unroll
        for (int r = 0; r < 4; ++r)
          Cp[(row + r) * R_SZ + col] = (bf16_t)acc[am][an][r];
      }
    }
  }
}

// ---------------- pass 1: E = exp(Q K^T / 16) (causal) pair-panels + row sums ----------------
// Flat grid 544 (= 4 b x 136 triangular tiles), XCD-chunked so same-Q-panel blocks share an L2.
__global__ __launch_bounds__(512) void ep8_kernel(
    const bf16_t* __restrict__ Qb, const bf16_t* __restrict__ Kb,
    bf16_t* __restrict__ E, float* __restrict__ lsum)
{
  extern __shared__ char lds[];
  const int f = blockIdx.x;                  // 0..543
  const int lg = (f & 7) * 68 + (f >> 3);    // bijective (544 = 8*68)
  const int b = lg / 136;
  const int t136 = lg - b * 136;
  int P = (int)((sqrtf((float)(8 * t136 + 1)) - 1.0f) * 0.5f);
  while ((P + 1) * (P + 2) / 2 <= t136) ++P;
  while (P * (P + 1) / 2 > t136) --P;
  const int Jp = t136 - P * (P + 1) / 2;     // 0..P

  f32x4 acc[8][4] = {};
  gemm8_core<true>((const char*)Qb + ((long)b * L_SZ + P * 256) * (R_SZ * 2),
                   (const char*)Kb + ((long)b * L_SZ + Jp * 256) * (R_SZ * 2),
                   R_SZ * 2, R_SZ * 2, R_SZ / 64, lds, acc);
  const int t = threadIdx.x, l = t & 63, wid = t >> 6;
  const int wr = wid >> 2, wc = wid & 3, l15 = l & 15, l4 = l >> 4;
  bf16_t* Ep = E + (long)b * E2_ELEMS + 32768L * P * (P + 1);
  const long ldaE = (long)(P + 1) * 256;
  float* lp = lsum + (long)b * L_SZ + P * 256;
  const bool diag = (Jp == P);
#pragma unroll
  for (int am = 0; am < 8; ++am) {
    const int rowi = wr * 16 + am * 32 + l4 * 4;   // 0..255 within pair rows
#pragma unroll
    for (int r = 0; r < 4; ++r) {
      float s = 0.0f;
#pragma unroll
      for (int an = 0; an < 4; ++an) {
        const int coli = wc * 16 + an * 64 + l15;
        float p = exp2f(acc[am][an][r] * EXP_SC);
        if (diag && coli > rowi + r) p = 0.0f;     // jj > ii (same 256-tile)
        Ep[(long)(rowi + r) * ldaE + Jp * 256 + coli] = (bf16_t)p;
        s += p;
      }
      s = rsum16(s);
      if (l15 == 0) atomicAdd(lp + rowi + r, s);
    }
  }
}

// ---------------- pass 2: out = (E @ V'^T) / l + bo, paired tiles for balance ----------------
// Flat grid 256; XCD-chunked swizzle: each XCD gets 4 pr-pairs x 8 j-slices, one b.
__global__ __launch_bounds__(512) void pv8_kernel(
    const bf16_t* __restrict__ E, const bf16_t* __restrict__ VT,
    const float* __restrict__ lsum, const float* __restrict__ bo,
    float* __restrict__ out)
{
  extern __shared__ char lds[];
  const int f = blockIdx.x;                 // 0..255
  const int lg = (f & 7) * 32 + (f >> 3);   // bijective (256 = 8*32)
  const int yj = lg & 7;
  const int pr = (lg >> 3) & 7;
  const int b  = lg >> 6;
  const int nBase = yj * 256;
  const int t = threadIdx.x, l = t & 63, wid = t >> 6;
  const int wr = wid >> 2, wc = wid & 3, l15 = l & 15, l4 = l >> 4;

#pragma unroll
  for (int s = 0; s < 2; ++s) {
    const int mt = s ? pr : (15 - pr);
    f32x4 acc[8][4] = {};
    const char* Ag = (const char*)E + (long)b * E2_BYTES + 65536L * mt * (mt + 1);
    const char* Bg = (const char*)VT + ((long)b * H_SZ + nBase) * (L_SZ * 2);
    gemm8_core<true>(Ag, Bg, (long)(mt + 1) * 512, L_SZ * 2, (mt + 1) * 4, lds, acc);
#pragma unroll
    for (int am = 0; am < 8; ++am) {
      const long rowG = (long)b * L_SZ + mt * 256 + wr * 16 + am * 32 + l4 * 4;
      float linv[4];
#pragma unroll
      for (int r = 0; r < 4; ++r) linv[r] = 1.0f / lsum[rowG + r];
#pragma unroll
      for (int an = 0; an < 4; ++an) {
        const int col = nBase + wc * 16 + an * 64 + l15;
        const float bias = bo[col];
#pragma unroll
        for (int r = 0; r < 4; ++r)
          out[(rowG + r) * H_SZ + col] = acc[am][an][r] * linv[r] + bias;
      }
    }
  }
}

extern "C" void kernel_launch(void* const* d_in, const int* in_sizes, int n_in,
                              void* d_out, int out_size, void* d_ws, size_t ws_size,
                              hipStream_t stream) {
  const float* x  = (const float*)d_in[0];
  const float* Ws = (const float*)d_in[1];
  const float* Wa = (const float*)d_in[2];
  const float* Wo = (const float*)d_in[3];
  const float* bo = (const float*)d_in[4];
  float* out = (float*)d_out;

  char* ws = (char*)d_ws;
  // layout (bytes):
  //   [0, 64M)        xb   (dead after V'/QK)  -- aliased by E pair-panels
  //   [64M, 65M)      Wst  (dead after QK)     -- aliased by E
  //   [65M, 66M)      Wat  (dead after QK)     -- aliased by E
  //   [66M, 74M)      Wob  (dead after V')     -- head aliased by E (E = 71.3MB < 74M)
  //   [74M, 82M)      Qb
  //   [82M, 90M)      Kb
  //   [90M, 154M)     VT
  //   [154M, +64K)    lsum
  bf16_t* xb  = (bf16_t*)(ws + 0);
  bf16_t* Wst = (bf16_t*)(ws + 67108864);
  bf16_t* Wat = (bf16_t*)(ws + 68157440);
  bf16_t* Wob = (bf16_t*)(ws + 69206016);
  bf16_t* Qb  = (bf16_t*)(ws + 77594624);
  bf16_t* Kb  = (bf16_t*)(ws + 85983232);
  bf16_t* VT  = (bf16_t*)(ws + 94371840);
  float*  lsum = (float*)(ws + 161480704);
  bf16_t* E   = (bf16_t*)(ws + 0);

  hipFuncSetAttribute((const void*)vq8_kernel, hipFuncAttributeMaxDynamicSharedMemorySize, LDS_BYTES);
  hipFuncSetAttribute((const void*)ep8_kernel, hipFuncAttributeMaxDynamicSharedMemorySize, LDS_BYTES);
  hipFuncSetAttribute((const void*)pv8_kernel, hipFuncAttributeMaxDynamicSharedMemorySize, LDS_BYTES);

  // conversions + lsum init (block-range partitioned; LDS-tiled Ws/Wa transpose)
  conv_kernel<<<dim3(2048), dim3(256), 0, stream>>>(x, Ws, Wa, Wo, xb, Wst, Wat, Wob, lsum);
  // fused: V'^T = Wo . x (512 full blocks) + Q = x @ Ws, K = x @ Wa (256 half-N blocks)
  vq8_kernel<<<dim3(768), dim3(512), LDS_BYTES, stream>>>(Wob, xb, VT, Wst, Wat, Qb, Kb);
  // pass 1: E = exp(QK^T/16) causal pair-panels + row sums (E aliases xb/W* — all dead now)
  ep8_kernel<<<dim3(544), dim3(512), LDS_BYTES, stream>>>(Qb, Kb, E, lsum);
  // pass 2: out = E @ V'^T / l + bo  (XCD-swizzled flat grid)
  pv8_kernel<<<dim3(256), dim3(512), LDS_BYTES, stream>>>(E, VT, lsum, bo, out);
}

// Round 17
// 365.538 us; speedup vs baseline: 1.0282x; 1.0017x over previous
//
#include <hip/hip_runtime.h>
#include <hip/hip_bf16.h>
#include <cstdint>
#include <cstddef>
#include <cmath>

typedef __bf16 bf16_t;
typedef __bf16 bf16x8 __attribute__((ext_vector_type(8)));
typedef __bf16 bf16x4v __attribute__((ext_vector_type(4)));
typedef float f32x4 __attribute__((ext_vector_type(4)));

#define B_SZ 4
#define L_SZ 4096
#define H_SZ 2048
#define R_SZ 256
// exp(S) with S = acc/16  ->  2^(acc * log2(e)/16)
#define EXP_SC 0.090168440f
// E pair-panel geometry: pair P holds 256 rows x (P+1)*256 cols bf16
#define E2_ELEMS 8912896L   // 65536 * (1+2+...+16) elements per batch
#define E2_BYTES 17825792L
#define LDS_BYTES 163840    // A ring-4 (64K) + B ring-6 (96K)

// async global->LDS, 16B per lane. LDS dest must be wave-uniform base (+lane*16 by HW).
#define GLDS16(gaddr, laddr)                                                    \
  __builtin_amdgcn_global_load_lds(                                             \
      (const __attribute__((address_space(1))) void*)(gaddr),                   \
      (__attribute__((address_space(3))) void*)(laddr), 16, 0, 0)

__device__ __forceinline__ f32x4 mfma16(bf16x8 a, bf16x8 b, f32x4 c) {
  return __builtin_amdgcn_mfma_f32_16x16x32_bf16(a, b, c, 0, 0, 0);
}

__device__ __forceinline__ float rsum16(float v) {
  v += __shfl_xor(v, 1, 16);
  v += __shfl_xor(v, 2, 16);
  v += __shfl_xor(v, 4, 16);
  v += __shfl_xor(v, 8, 16);
  return v;
}

// ---------------- conversion kernel (block-range partitioned, coalesced transpose) --------
__global__ void conv_kernel(const float* __restrict__ x, const float* __restrict__ Ws,
                            const float* __restrict__ Wa, const float* __restrict__ Wo,
                            bf16_t* __restrict__ xb, bf16_t* __restrict__ Wst,
                            bf16_t* __restrict__ Wat, bf16_t* __restrict__ Wob,
                            float* __restrict__ lsum) {
  const int bid = blockIdx.x;
  const int t = threadIdx.x;
  if (bid < 1280) {
    const int tid = bid * 256 + t;
    const int stride = 1280 * 256;
    const int n4 = B_SZ * L_SZ * H_SZ / 4;
    for (int i = tid; i < n4; i += stride) {
      float4 v = reinterpret_cast<const float4*>(x)[i];
      bf16x4v o;
      o[0] = (bf16_t)v.x; o[1] = (bf16_t)v.y; o[2] = (bf16_t)v.z; o[3] = (bf16_t)v.w;
      reinterpret_cast<bf16x4v*>(xb)[i] = o;
    }
  } else if (bid < 1920) {
    const int tid = (bid - 1280) * 256 + t;
    const int stride = 640 * 256;
    for (int idx = tid; idx < H_SZ * H_SZ / 4; idx += stride) {
      float4 v = reinterpret_cast<const float4*>(Wo)[idx];
      bf16x4v o;
      o[0] = (bf16_t)v.x; o[1] = (bf16_t)v.y; o[2] = (bf16_t)v.z; o[3] = (bf16_t)v.w;
      reinterpret_cast<bf16x4v*>(Wob)[idx] = o;
    }
  } else if (bid < 2040) {
    __shared__ float tile[32][33];
    const int j = t & 31;
    const int i4 = t >> 5;
    for (int tt = bid - 1920; tt < 1024; tt += 120) {
      const int mat = tt >> 9;
      const int ti = tt & 511;
      const int h0 = (ti >> 3) * 32;
      const int r0 = (ti & 7) * 32;
      const float* src = mat ? Wa : Ws;
      bf16_t* dst = mat ? Wat : Wst;
      __syncthreads();
#pragma unroll
      for (int p = 0; p < 4; ++p) {
        const int ii = p * 8 + i4;
        tile[ii][j] = src[(long)(h0 + ii) * R_SZ + r0 + j];
      }
      __syncthreads();
#pragma unroll
      for (int p = 0; p < 4; ++p) {
        const int rr = p * 8 + i4;
        dst[(long)(r0 + rr) * H_SZ + h0 + j] = (bf16_t)tile[j][rr];
      }
    }
  } else {
    const int tid = (bid - 2040) * 256 + t;
    const int stride = 8 * 256;
    for (int idx = tid; idx < B_SZ * L_SZ; idx += stride) lsum[idx] = 0.0f;
  }
}

// ===== 256x256 GEMM core — 2-barrier tile, B ring-6, compiler-managed lgkm waits (R14) =====
// C[m,n] = sum_k A[m,k] B[n,k]. K = NT*64 (NT >= 4). 512 threads = 8 waves (2M x 4N).
// LDS 160 KiB: A [0,64K) = 4 half-slots (slot = A-half h & 3); B [64K,160K) = 6 half-slots
// (slot = B-half h % 6). Half-slot = 128 rows x 128 B linear, swizzle via pre-swizzled
// global source; reads XOR the same mask. FULLN=false -> N=128.
// No explicit lgkmcnt waits in the steady loop: every ds_read is consumed by an MFMA in its
// own region, so the compiler's per-MFMA counted lgkmcnt waits give minimal head stall and
// guarantee reads drain before the region-end barrier. vmcnt certification per R13's
// induction. Measured best: 366.2 µs total (R14).

#define G8_STG(P, REGION, BUFOFF, HALF)                                        \
  GLDS16((P)[0], lds + (REGION) + (BUFOFF) + (HALF)*16384 + ldst0);            \
  GLDS16((P)[1], lds + (REGION) + (BUFOFF) + (HALF)*16384 + ldst1);            \
  (P)[0] += 128; (P)[1] += 128;

// B stage into ring slot S (0..5)
#define GB_STG(P, S)                                                           \
  GLDS16((P)[0], lds + 65536 + (S)*16384 + ldst0);                             \
  GLDS16((P)[1], lds + 65536 + (S)*16384 + ldst1);                             \
  (P)[0] += 128; (P)[1] += 128;

#define G8_LDA(MH, BO) {                                                       \
  const char* ap_ = lds + (BO) + (MH)*16384;                                   \
  fa[0][0] = *(const bf16x8*)(ap_ + aOff0);                                    \
  fa[0][1] = *(const bf16x8*)(ap_ + aOff1);                                    \
  fa[1][0] = *(const bf16x8*)(ap_ + 4096 + aOff0);                             \
  fa[1][1] = *(const bf16x8*)(ap_ + 4096 + aOff1);                             \
  fa[2][0] = *(const bf16x8*)(ap_ + 8192 + aOff0);                             \
  fa[2][1] = *(const bf16x8*)(ap_ + 8192 + aOff1);                             \
  fa[3][0] = *(const bf16x8*)(ap_ + 12288 + aOff0);                            \
  fa[3][1] = *(const bf16x8*)(ap_ + 12288 + aOff1); }

// B frag read from ring slot S+NH
#define G8_LDB(NH, S) {                                                        \
  const char* bp_ = lds + 65536 + ((S) + (NH)) * 16384;                        \
  fb[NH][0][0] = *(const bf16x8*)(bp_ + bOff0);                                \
  fb[NH][0][1] = *(const bf16x8*)(bp_ + bOff1);                                \
  fb[NH][1][0] = *(const bf16x8*)(bp_ + 8192 + bOff0);                         \
  fb[NH][1][1] = *(const bf16x8*)(bp_ + 8192 + bOff1); }

#define G8_MM1(AM, AN, MF, NH, J)                                              \
  acc[AM][AN] = mfma16(fa[MF][1], fb[NH][J][1],                                \
                 mfma16(fa[MF][0], fb[NH][J][0], acc[AM][AN]))

#define G8_MM(MH, NH)                                                          \
  G8_MM1((MH)*4+0, (NH)*2+0, 0, NH, 0); G8_MM1((MH)*4+0, (NH)*2+1, 0, NH, 1); \
  G8_MM1((MH)*4+1, (NH)*2+0, 1, NH, 0); G8_MM1((MH)*4+1, (NH)*2+1, 1, NH, 1); \
  G8_MM1((MH)*4+2, (NH)*2+0, 2, NH, 0); G8_MM1((MH)*4+2, (NH)*2+1, 2, NH, 1); \
  G8_MM1((MH)*4+3, (NH)*2+0, 3, NH, 0); G8_MM1((MH)*4+3, (NH)*2+1, 3, NH, 1)

template <bool FULLN>
__device__ __forceinline__ void gemm8_core(
    const char* Ag, const char* Bg, long aRowB, long bRowB, int NT,
    char* lds, f32x4 (&acc)[8][4])
{
  const int t = threadIdx.x;
  const int l = t & 63;
  const int wid = t >> 6;
  const int wr = wid >> 2;
  const int wc = wid & 3;
  const int l15 = l & 15;
  const int l4 = l >> 4;
  const int swzm = (l15 & 7) << 4;
  const int aOff0 = (wr * 16 + l15) * 128 + ((l4 * 16) ^ swzm);
  const int aOff1 = (wr * 16 + l15) * 128 + ((64 + l4 * 16) ^ swzm);
  const int bOff0 = (wc * 16 + l15) * 128 + ((l4 * 16) ^ swzm);
  const int bOff1 = (wc * 16 + l15) * 128 + ((64 + l4 * 16) ^ swzm);
  // staging: per-thread, 2 x 16B per half-tile; d = t*16 + i*8192 covers [0,16K) linear
  const int d0 = t * 16, d1 = t * 16 + 8192;
  const int r0 = d0 >> 7, r1 = d1 >> 7;
  const int s0 = (d0 & 127) ^ ((r0 & 7) << 4);
  const int s1 = (d1 & 127) ^ ((r1 & 7) << 4);
  const char* pA0[2] = { Ag + (long)r0 * aRowB + s0, Ag + (long)r1 * aRowB + s1 };
  const char* pA1[2] = { Ag + (long)(128 + r0) * aRowB + s0, Ag + (long)(128 + r1) * aRowB + s1 };
  const char* pB0[2] = { Bg + (long)r0 * bRowB + s0, Bg + (long)r1 * bRowB + s1 };
  const char* pB1[2] = { Bg + (long)(128 + r0) * bRowB + s0, Bg + (long)(128 + r1) * bRowB + s1 };
  const int ldst0 = wid * 1024, ldst1 = wid * 1024 + 8192;
  bf16x8 fa[4][2], fb[2][2][2];

  // prologue. Issue order matters for the counted vmcnt:
  //   group 1: A(0), A(1), B(0)[, B(1)]  -- tile 0, must retire before first barrier
  //   group 2: A(2), B(2)[, B(3)]        -- tile 1, stays in flight
  G8_STG(pA0, 0, 0, 0);          // A half 0 -> slot 0
  G8_STG(pA1, 0, 0, 1);          // A half 1 -> slot 1
  GB_STG(pB0, 0);                // B half 0 -> slot 0
  if constexpr (FULLN) { GB_STG(pB1, 1); }   // B half 1 -> slot 1
  G8_STG(pA0, 0, 32768, 0);      // A half 2 -> slot 2
  GB_STG(pB0, 2);                // B half 2 -> slot 2
  if constexpr (FULLN) { GB_STG(pB1, 3); }   // B half 3 -> slot 3
  if constexpr (FULLN) {
    asm volatile("s_waitcnt vmcnt(6)" ::: "memory");   // retire A(0),A(1),B(0),B(1)
  } else {
    asm volatile("s_waitcnt vmcnt(4)" ::: "memory");   // retire A(0),A(1),B(0)
  }
  __builtin_amdgcn_sched_barrier(0);
  __builtin_amdgcn_s_barrier();

  int bufOff = 0;   // A slot base: (2T)&3 halves -> byte offset {0,32768}
  int b0s = 0;      // B ring: (2T)%6
  for (int T = 0; T < NT; ++T) {
    const int ob = bufOff ^ 32768;
    const bool stg1 = (T < NT - 1);   // A(2T+3) exists
    const bool stg2 = (T < NT - 2);   // A(2T+4), B(2T+4), B(2T+5) exist
    const int s4 = (b0s + 4 >= 6) ? (b0s - 2) : (b0s + 4);   // slot of B half 2T+4
    // ---- region 1 ----
    G8_LDA(0, bufOff);
    G8_LDB(0, b0s);
    if constexpr (FULLN) { G8_LDB(1, b0s); }
    if (stg1) { G8_STG(pA1, 0, ob, 1); }           // A(2T+3)
    if (stg2) {
      GB_STG(pB0, s4);                              // B(2T+4)
      if constexpr (FULLN) { GB_STG(pB1, s4 + 1); } // B(2T+5)
    }
    __builtin_amdgcn_s_setprio(1);
    G8_MM(0, 0);
    if constexpr (FULLN) { G8_MM(0, 1); }
    __builtin_amdgcn_s_setprio(0);
    G8_LDA(1, bufOff);
    __builtin_amdgcn_sched_barrier(0);
    __builtin_amdgcn_s_barrier();
    // ---- region 2 ----
    if (stg2) { G8_STG(pA0, 0, bufOff, 0); }        // A(2T+4)
    __builtin_amdgcn_s_setprio(1);
    G8_MM(1, 0);
    if constexpr (FULLN) { G8_MM(1, 1); }
    __builtin_amdgcn_s_setprio(0);
    if (stg2) {
      // retire exactly tile T+1's halves; leave {B(2T+4),B(2T+5),A(2T+4)} in flight
      if constexpr (FULLN) {
        asm volatile("s_waitcnt vmcnt(6)" ::: "memory");
      } else {
        asm volatile("s_waitcnt vmcnt(4)" ::: "memory");
      }
    } else if (stg1) {
      asm volatile("s_waitcnt vmcnt(0)" ::: "memory");
    }
    __builtin_amdgcn_sched_barrier(0);
    __builtin_amdgcn_s_barrier();
    bufOff ^= 32768;
    b0s += 2; if (b0s >= 6) b0s -= 6;
  }
}

// ---------------- fused V'+QK GEMM kernel ----------------
// Flat grid 768 = 512 V' full blocks (f<512, XCD-chunked) + 256 QK half-N blocks (f>=512,
// N=128). Exactly 3 blocks/CU.
__global__ __launch_bounds__(512) void vq8_kernel(
    const bf16_t* __restrict__ Wob, const bf16_t* __restrict__ xb, bf16_t* __restrict__ VT,
    const bf16_t* __restrict__ Wst, const bf16_t* __restrict__ Wat,
    bf16_t* __restrict__ Qb, bf16_t* __restrict__ Kb)
{
  extern __shared__ char lds[];
  const int f = blockIdx.x;
  const int t = threadIdx.x, l = t & 63, wid = t >> 6;
  const int wr = wid >> 2, wc = wid & 3, l15 = l & 15, l4 = l >> 4;
  f32x4 acc[8][4] = {};
  if (f < 512) {
    const int lg = (f & 7) * 64 + (f >> 3);   // bijective (512 = 8*64)
    const int xo = lg & 7;
    const int yj = (lg >> 3) & 15;
    const int b  = lg >> 7;
    const long mBase = (long)xo * 256;        // o
    const long nBase = (long)yj * 256;        // j
    gemm8_core<true>((const char*)Wob + mBase * (H_SZ * 2),
                     (const char*)xb + ((long)b * L_SZ + nBase) * (H_SZ * 2),
                     H_SZ * 2, H_SZ * 2, H_SZ / 64, lds, acc);
    bf16_t* Cp = VT + (long)b * H_SZ * L_SZ;
#pragma unroll
    for (int am = 0; am < 8; ++am) {
#pragma unroll
      for (int an = 0; an < 4; ++an) {
        const long row = mBase + wr * 16 + am * 32 + l4 * 4;
        const long col = nBase + wc * 16 + an * 64 + l15;
#pragma unroll
        for (int r = 0; r < 4; ++r)
          Cp[(row + r) * L_SZ + col] = (bf16_t)acc[am][an][r];
      }
    }
  } else {
    const int qf = f - 512;                   // 0..255
    const int lg = (qf & 7) * 32 + (qf >> 3); // bijective (256 = 8*32)
    const int m = lg & 63;
    const int n = (lg >> 6) & 1;
    const int proj = lg >> 7;
    const long mBase = (long)m * 256;
    const long nBase = (long)n * 128;
    const bf16_t* W = proj ? Wat : Wst;
    bf16_t* Cp = proj ? Kb : Qb;
    gemm8_core<false>((const char*)xb + mBase * (H_SZ * 2),
                      (const char*)W + nBase * (H_SZ * 2),
                      H_SZ * 2, H_SZ * 2, H_SZ / 64, lds, acc);
#pragma unroll
    for (int am = 0; am < 8; ++am) {
#pragma unroll
      for (int an = 0; an < 2; ++an) {
        const long row = mBase + wr * 16 + am * 32 + l4 * 4;
        const long col = nBase + wc * 16 + an * 64 + l15;
#pragma unroll
        for (int r = 0; r < 4; ++r)
          Cp[(row + r) * R_SZ + col] = (bf16_t)acc[am][an][r];
      }
    }
  }
}

// ---------------- pass 1: E = exp(Q K^T / 16) (causal) pair-panels + row sums ----------------
// Flat grid 544 (= 4 b x 136 triangular tiles), XCD-chunked so same-Q-panel blocks share an L2.
__global__ __launch_bounds__(512) void ep8_kernel(
    const bf16_t* __restrict__ Qb, const bf16_t* __restrict__ Kb,
    bf16_t* __restrict__ E, float* __restrict__ lsum)
{
  extern __shared__ char lds[];
  const int f = blockIdx.x;                  // 0..543
  const int lg = (f & 7) * 68 + (f >> 3);    // bijective (544 = 8*68)
  const int b = lg / 136;
  const int t136 = lg - b * 136;
  int P = (int)((sqrtf((float)(8 * t136 + 1)) - 1.0f) * 0.5f);
  while ((P + 1) * (P + 2) / 2 <= t136) ++P;
  while (P * (P + 1) / 2 > t136) --P;
  const int Jp = t136 - P * (P + 1) / 2;     // 0..P

  f32x4 acc[8][4] = {};
  gemm8_core<true>((const char*)Qb + ((long)b * L_SZ + P * 256) * (R_SZ * 2),
                   (const char*)Kb + ((long)b * L_SZ + Jp * 256) * (R_SZ * 2),
                   R_SZ * 2, R_SZ * 2, R_SZ / 64, lds, acc);
  const int t = threadIdx.x, l = t & 63, wid = t >> 6;
  const int wr = wid >> 2, wc = wid & 3, l15 = l & 15, l4 = l >> 4;
  bf16_t* Ep = E + (long)b * E2_ELEMS + 32768L * P * (P + 1);
  const long ldaE = (long)(P + 1) * 256;
  float* lp = lsum + (long)b * L_SZ + P * 256;
  const bool diag = (Jp == P);
#pragma unroll
  for (int am = 0; am < 8; ++am) {
    const int rowi = wr * 16 + am * 32 + l4 * 4;   // 0..255 within pair rows
#pragma unroll
    for (int r = 0; r < 4; ++r) {
      float s = 0.0f;
#pragma unroll
      for (int an = 0; an < 4; ++an) {
        const int coli = wc * 16 + an * 64 + l15;
        float p = exp2f(acc[am][an][r] * EXP_SC);
        if (diag && coli > rowi + r) p = 0.0f;     // jj > ii (same 256-tile)
        Ep[(long)(rowi + r) * ldaE + Jp * 256 + coli] = (bf16_t)p;
        s += p;
      }
      s = rsum16(s);
      if (l15 == 0) atomicAdd(lp + rowi + r, s);
    }
  }
}

// ---------------- pass 2: out = (E @ V'^T) / l + bo, paired tiles for balance ----------------
// Flat grid 256; XCD-chunked swizzle: each XCD gets 4 pr-pairs x 8 j-slices, one b.
__global__ __launch_bounds__(512) void pv8_kernel(
    const bf16_t* __restrict__ E, const bf16_t* __restrict__ VT,
    const float* __restrict__ lsum, const float* __restrict__ bo,
    float* __restrict__ out)
{
  extern __shared__ char lds[];
  const int f = blockIdx.x;                 // 0..255
  const int lg = (f & 7) * 32 + (f >> 3);   // bijective (256 = 8*32)
  const int yj = lg & 7;
  const int pr = (lg >> 3) & 7;
  const int b  = lg >> 6;
  const int nBase = yj * 256;
  const int t = threadIdx.x, l = t & 63, wid = t >> 6;
  const int wr = wid >> 2, wc = wid & 3, l15 = l & 15, l4 = l >> 4;

#pragma unroll
  for (int s = 0; s < 2; ++s) {
    const int mt = s ? pr : (15 - pr);
    f32x4 acc[8][4] = {};
    const char* Ag = (const char*)E + (long)b * E2_BYTES + 65536L * mt * (mt + 1);
    const char* Bg = (const char*)VT + ((long)b * H_SZ + nBase) * (L_SZ * 2);
    gemm8_core<true>(Ag, Bg, (long)(mt + 1) * 512, L_SZ * 2, (mt + 1) * 4, lds, acc);
#pragma unroll
    for (int am = 0; am < 8; ++am) {
      const long rowG = (long)b * L_SZ + mt * 256 + wr * 16 + am * 32 + l4 * 4;
      float linv[4];
#pragma unroll
      for (int r = 0; r < 4; ++r) linv[r] = 1.0f / lsum[rowG + r];
#pragma unroll
      for (int an = 0; an < 4; ++an) {
        const int col = nBase + wc * 16 + an * 64 + l15;
        const float bias = bo[col];
#pragma unroll
        for (int r = 0; r < 4; ++r)
          out[(rowG + r) * H_SZ + col] = acc[am][an][r] * linv[r] + bias;
      }
    }
  }
}

extern "C" void kernel_launch(void* const* d_in, const int* in_sizes, int n_in,
                              void* d_out, int out_size, void* d_ws, size_t ws_size,
                              hipStream_t stream) {
  const float* x  = (const float*)d_in[0];
  const float* Ws = (const float*)d_in[1];
  const float* Wa = (const float*)d_in[2];
  const float* Wo = (const float*)d_in[3];
  const float* bo = (const float*)d_in[4];
  float* out = (float*)d_out;

  char* ws = (char*)d_ws;
  // layout (bytes):
  //   [0, 64M)        xb   (dead after V'/QK)  -- aliased by E pair-panels
  //   [64M, 65M)      Wst  (dead after QK)     -- aliased by E
  //   [65M, 66M)      Wat  (dead after QK)     -- aliased by E
  //   [66M, 74M)      Wob  (dead after V')     -- head aliased by E (E = 71.3MB < 74M)
  //   [74M, 82M)      Qb
  //   [82M, 90M)      Kb
  //   [90M, 154M)     VT
  //   [154M, +64K)    lsum
  bf16_t* xb  = (bf16_t*)(ws + 0);
  bf16_t* Wst = (bf16_t*)(ws + 67108864);
  bf16_t* Wat = (bf16_t*)(ws + 68157440);
  bf16_t* Wob = (bf16_t*)(ws + 69206016);
  bf16_t* Qb  = (bf16_t*)(ws + 77594624);
  bf16_t* Kb  = (bf16_t*)(ws + 85983232);
  bf16_t* VT  = (bf16_t*)(ws + 94371840);
  float*  lsum = (float*)(ws + 161480704);
  bf16_t* E   = (bf16_t*)(ws + 0);

  hipFuncSetAttribute((const void*)vq8_kernel, hipFuncAttributeMaxDynamicSharedMemorySize, LDS_BYTES);
  hipFuncSetAttribute((const void*)ep8_kernel, hipFuncAttributeMaxDynamicSharedMemorySize, LDS_BYTES);
  hipFuncSetAttribute((const void*)pv8_kernel, hipFuncAttributeMaxDynamicSharedMemorySize, LDS_BYTES);

  // conversions + lsum init (block-range partitioned; LDS-tiled Ws/Wa transpose)
  conv_kernel<<<dim3(2048), dim3(256), 0, stream>>>(x, Ws, Wa, Wo, xb, Wst, Wat, Wob, lsum);
  // fused: V'^T = Wo . x (512 full blocks) + Q = x @ Ws, K = x @ Wa (256 half-N blocks)
  vq8_kernel<<<dim3(768), dim3(512), LDS_BYTES, stream>>>(Wob, xb, VT, Wst, Wat, Qb, Kb);
  // pass 1: E = exp(QK^T/16) causal pair-panels + row sums (E aliases xb/W* — all dead now)
  ep8_kernel<<<dim3(544), dim3(512), LDS_BYTES, stream>>>(Qb, Kb, E, lsum);
  // pass 2: out = E @ V'^T / l + bo  (XCD-swizzled flat grid)
  pv8_kernel<<<dim3(256), dim3(512), LDS_BYTES, stream>>>(E, VT, lsum, bo, out);
}